// Round 14
// baseline (1801.349 us; speedup 1.0000x reference)
//
#include <hip/hip_runtime.h>
#include <cmath>
#include <cstdint>
#include <cstddef>

#define BB 256      // batch
#define MM 8192     // checks
#define NN 16384    // variables
#define DEG 10
#define MAX_ITER 30
#define PAR_BLOCKS 64
#define NXCD 8
#define GRP 32      // batches per XCD group (BB / NXCD)

typedef unsigned char  u8;
typedef unsigned short u16;

// ---------------- prologue kernels ----------------

__global__ void k_init(int* colcnt, int* colfill, int* mm, int* niter, int* conv, int* cnt) {
    int t = blockIdx.x * blockDim.x + threadIdx.x;
    if (t < NN) { colcnt[t] = 0; colfill[t] = 0; }
    if (t < BB) { mm[t] = 0; niter[t] = -1; conv[t] = 0; }
    if (t == 0) *cnt = 0;
}

// transpose f32: in (R,C) row-major -> out (C,R); optional duplicate out2
__global__ void k_transpose_f32(const float* __restrict__ in, float* __restrict__ out,
                                float* __restrict__ out2, int R, int C) {
    __shared__ float tile[64][65];
    int c0 = blockIdx.x * 64;
    int r0 = blockIdx.y * 64;
    #pragma unroll
    for (int k = 0; k < 16; k++) {
        int idx = k * 256 + threadIdx.x;
        int i = idx >> 6, j = idx & 63;
        tile[i][j] = in[(size_t)(r0 + i) * C + (c0 + j)];
    }
    __syncthreads();
    #pragma unroll
    for (int k = 0; k < 16; k++) {
        int idx = k * 256 + threadIdx.x;
        int i = idx >> 6, j = idx & 63;
        float v = tile[j][i];
        size_t o = (size_t)(c0 + i) * R + (r0 + j);
        out[o] = v;
        if (out2) out2[o] = v;
    }
}

// synd (B,M) f32 -> syndb (M,B) byte
__global__ void k_synd_t(const float* __restrict__ synd, u8* __restrict__ syndb) {
    __shared__ float tile[64][65];
    int c0 = blockIdx.x * 64;   // m
    int r0 = blockIdx.y * 64;   // b
    #pragma unroll
    for (int k = 0; k < 16; k++) {
        int idx = k * 256 + threadIdx.x;
        int i = idx >> 6, j = idx & 63;
        tile[i][j] = synd[(size_t)(r0 + i) * MM + (c0 + j)];
    }
    __syncthreads();
    #pragma unroll
    for (int k = 0; k < 16; k++) {
        int idx = k * 256 + threadIdx.x;
        int i = idx >> 6, j = idx & 63;
        syndb[(size_t)(c0 + i) * BB + (r0 + j)] = (tile[j][i] != 0.0f) ? 1 : 0;
    }
}

__global__ void k_hist(const int* __restrict__ vc, int* colcnt) {
    int e = blockIdx.x * 256 + threadIdx.x;
    if (e >= MM * DEG) return;
    int c = vc[e];
    if (c < NN) atomicAdd(&colcnt[c], 1);
}

__global__ void k_scan(const int* __restrict__ colcnt, int* __restrict__ colptr) {
    __shared__ int part[256];
    __shared__ int base[257];
    int t = threadIdx.x;
    int s = 0;
    for (int i = 0; i < 64; i++) s += colcnt[t * 64 + i];
    part[t] = s;
    __syncthreads();
    if (t == 0) {
        int acc = 0;
        for (int i = 0; i < 256; i++) { base[i] = acc; acc += part[i]; }
        base[256] = acc;
    }
    __syncthreads();
    int acc = base[t];
    for (int i = 0; i < 64; i++) { int c = t * 64 + i; colptr[c] = acc; acc += colcnt[c]; }
    if (t == 255) colptr[NN] = base[256];
}

__global__ void k_fill(const int* __restrict__ vc, const int* __restrict__ colptr,
                       int* colfill, int* coledges) {
    int e = blockIdx.x * 256 + threadIdx.x;
    if (e >= MM * DEG) return;
    int c = vc[e];
    if (c < NN) {
        int p = colptr[c] + atomicAdd(&colfill[c], 1);
        coledges[p] = e;
    }
}

// deterministic: sort each column's edge list ascending (order-independent result)
__global__ void k_sort(const int* __restrict__ colptr, int* coledges) {
    int n = blockIdx.x * 256 + threadIdx.x;
    if (n >= NN) return;
    int p0 = colptr[n], p1 = colptr[n + 1];
    for (int i = p0 + 1; i < p1; i++) {
        int v = coledges[i];
        int j = i - 1;
        while (j >= p0 && coledges[j] > v) { coledges[j + 1] = coledges[j]; j--; }
        coledges[j + 1] = v;
    }
}

// posinfo[p] = (m << 8) | d  (m*BB in high bits since BB=256; d in low 4)
__global__ void k_pos(const int* __restrict__ coledges, const int* __restrict__ colptr,
                      int* __restrict__ posinfo) {
    int p = blockIdx.x * 256 + threadIdx.x;
    if (p >= colptr[NN]) return;
    int e = coledges[p];
    int m = e / DEG;
    int d = e - m * DEG;
    posinfo[p] = (m << 8) | d;
}

// ---------------- iteration kernels ----------------

// check-node update, XCD-partitioned, 8 batches per thread (two float4 halves
// 64B apart -> same 128B line). bid&7 = batch group g, bid>>3 = row chunk of 64.
// thread t: row = chunk*64 + (t>>2), halves at b4a = 32g + (t&3)*4 and b4a+16.
// State per (m,b): svv interleaved {v0,v1} (v0=beta*min0, v1=beta*min1),
// sbits = neg(10b) | q<<10 | i0<<11. Prev-message reconstruction is bit-exact:
// +-1 multiplies exact; (d==i0) <=> (ab[d]==min0) since dup mins force min1==min0.
__global__ void k_check8(const int* __restrict__ vc, const float* __restrict__ lv,
                         float* __restrict__ svv, u16* __restrict__ sbits,
                         const u8* __restrict__ syndb, float beta, int first) {
    __shared__ int cs[64 * DEG];
    int bid = blockIdx.x, t = threadIdx.x;
    int g = bid & (NXCD - 1);
    int r0 = (bid >> 3) * 64;
    for (int i = t; i < 64 * DEG; i += 256) cs[i] = vc[r0 * DEG + i];
    __syncthreads();

    int row = t >> 2;
    int m = r0 + row;
    int b4a = g * GRP + (t & 3) * 4;
    size_t mba = (size_t)m * BB + b4a;
    size_t mbb = mba + 16;

    float pv0[8], pv1[8];
    unsigned pb[8];
    if (!first) {
        float4 qa0 = *(const float4*)(svv + mba * 2);
        float4 qa1 = *(const float4*)(svv + mba * 2 + 4);
        float4 qb0 = *(const float4*)(svv + mbb * 2);
        float4 qb1 = *(const float4*)(svv + mbb * 2 + 4);
        ushort4 pa = *(const ushort4*)(sbits + mba);
        ushort4 pbv = *(const ushort4*)(sbits + mbb);
        pv0[0] = qa0.x; pv1[0] = qa0.y; pv0[1] = qa0.z; pv1[1] = qa0.w;
        pv0[2] = qa1.x; pv1[2] = qa1.y; pv0[3] = qa1.z; pv1[3] = qa1.w;
        pv0[4] = qb0.x; pv1[4] = qb0.y; pv0[5] = qb0.z; pv1[5] = qb0.w;
        pv0[6] = qb1.x; pv1[6] = qb1.y; pv0[7] = qb1.z; pv1[7] = qb1.w;
        pb[0] = pa.x;  pb[1] = pa.y;  pb[2] = pa.z;  pb[3] = pa.w;
        pb[4] = pbv.x; pb[5] = pbv.y; pb[6] = pbv.z; pb[7] = pbv.w;
    } else {
        #pragma unroll
        for (int j = 0; j < 8; j++) { pv0[j] = 0.f; pv1[j] = 0.f; pb[j] = 0; }
    }
    int pi0[8]; unsigned pq[8];
    #pragma unroll
    for (int j = 0; j < 8; j++) { pi0[j] = (pb[j] >> 11) & 15; pq[j] = (pb[j] >> 10) & 1u; }

    float m0[8], m1[8];
    unsigned neg[8];
    int i0[8];
    #pragma unroll
    for (int j = 0; j < 8; j++) { m0[j] = INFINITY; m1[j] = INFINITY; neg[j] = 0; i0[j] = 0; }

    #pragma unroll
    for (int d = 0; d < DEG; d++) {
        int c = cs[row * DEG + d];
        if (c >= NN) continue;   // dummy edge: a=+inf -> no sign bit, no min update
        float4 ga = *(const float4*)(lv + (size_t)c * BB + b4a);
        float4 gb = *(const float4*)(lv + (size_t)c * BB + b4a + 16);
        float gj[8] = {ga.x, ga.y, ga.z, ga.w, gb.x, gb.y, gb.z, gb.w};
        #pragma unroll
        for (int j = 0; j < 8; j++) {
            float a;
            if (first) a = gj[j];
            else {
                float tt = (d == pi0[j]) ? pv1[j] : pv0[j];
                unsigned sx = pq[j] ^ ((pb[j] >> d) & 1u);
                a = gj[j] - (sx ? -tt : tt);
            }
            if (!(a > 0.0f)) neg[j] |= 1u << d;   // sign(0) -> -1 semantics
            float x = fabsf(a);
            if (x < m0[j]) { m1[j] = m0[j]; m0[j] = x; i0[j] = d; }
            else if (x < m1[j]) m1[j] = x;
        }
    }

    uchar4 sba = *(const uchar4*)(syndb + mba);
    uchar4 sbb = *(const uchar4*)(syndb + mbb);
    unsigned sbv[8] = {sba.x, sba.y, sba.z, sba.w, sbb.x, sbb.y, sbb.z, sbb.w};
    unsigned q[8];
    float v0[8], v1[8];
    #pragma unroll
    for (int j = 0; j < 8; j++) {
        q[j] = (__popc(neg[j]) & 1u) ^ (sbv[j] ? 1u : 0u);
        v0[j] = beta * m0[j];
        v1[j] = beta * m1[j];
    }

    *(float4*)(svv + mba * 2)     = make_float4(v0[0], v1[0], v0[1], v1[1]);
    *(float4*)(svv + mba * 2 + 4) = make_float4(v0[2], v1[2], v0[3], v1[3]);
    *(float4*)(svv + mbb * 2)     = make_float4(v0[4], v1[4], v0[5], v1[5]);
    *(float4*)(svv + mbb * 2 + 4) = make_float4(v0[6], v1[6], v0[7], v1[7]);
    ushort4 nba, nbb;
    nba.x = (u16)(neg[0] | (q[0] << 10) | ((unsigned)i0[0] << 11));
    nba.y = (u16)(neg[1] | (q[1] << 10) | ((unsigned)i0[1] << 11));
    nba.z = (u16)(neg[2] | (q[2] << 10) | ((unsigned)i0[2] << 11));
    nba.w = (u16)(neg[3] | (q[3] << 10) | ((unsigned)i0[3] << 11));
    nbb.x = (u16)(neg[4] | (q[4] << 10) | ((unsigned)i0[4] << 11));
    nbb.y = (u16)(neg[5] | (q[5] << 10) | ((unsigned)i0[5] << 11));
    nbb.z = (u16)(neg[6] | (q[6] << 10) | ((unsigned)i0[6] << 11));
    nbb.w = (u16)(neg[7] | (q[7] << 10) | ((unsigned)i0[7] << 11));
    *(ushort4*)(sbits + mba) = nba;
    *(ushort4*)(sbits + mbb) = nbb;
}

// variable-node update, XCD-partitioned, 8 batches per thread (same halves).
// Deterministic ascending-edge sum; messages reconstructed bit-exactly from
// the state planes; posinfo removes the per-edge division.
__global__ void k_var8(const float* __restrict__ llr0t, const float* __restrict__ svv,
                       const u16* __restrict__ sbits,
                       const int* __restrict__ colptr, const int* __restrict__ posinfo,
                       float* __restrict__ lv, const int* __restrict__ niter) {
    int bid = blockIdx.x, t = threadIdx.x;
    int g = bid & (NXCD - 1);
    int n = (bid >> 3) * 64 + (t >> 2);
    int b4a = g * GRP + (t & 3) * 4;
    int b4b = b4a + 16;

    int4 fa = *(const int4*)(niter + b4a);
    int4 fb = *(const int4*)(niter + b4b);
    bool liveA = (fa.x == -1) || (fa.y == -1) || (fa.z == -1) || (fa.w == -1);
    bool liveB = (fb.x == -1) || (fb.y == -1) || (fb.z == -1) || (fb.w == -1);
    if (!liveA && !liveB) return;

    float4 sA = *(const float4*)(llr0t + (size_t)n * BB + b4a);
    float4 sB = *(const float4*)(llr0t + (size_t)n * BB + b4b);
    int p0 = colptr[n], p1 = colptr[n + 1];
    for (int pp = p0; pp < p1; pp++) {
        unsigned pinfo = (unsigned)posinfo[pp];
        int d = pinfo & 15;
        size_t mba = (size_t)(pinfo & 0xFFFFFF00u) + b4a;
        const float* base = svv + mba * 2;
        float4 qa0 = *(const float4*)(base);
        float4 qa1 = *(const float4*)(base + 4);
        float4 qb0 = *(const float4*)(base + 32);
        float4 qb1 = *(const float4*)(base + 36);
        ushort4 ba = *(const ushort4*)(sbits + mba);
        ushort4 bb = *(const ushort4*)(sbits + mba + 16);
        {
            float tt = (d == ((ba.x >> 11) & 15)) ? qa0.y : qa0.x;
            unsigned sx = ((ba.x >> 10) ^ (ba.x >> d)) & 1u;
            sA.x += sx ? -tt : tt;
        }
        {
            float tt = (d == ((ba.y >> 11) & 15)) ? qa0.w : qa0.z;
            unsigned sx = ((ba.y >> 10) ^ (ba.y >> d)) & 1u;
            sA.y += sx ? -tt : tt;
        }
        {
            float tt = (d == ((ba.z >> 11) & 15)) ? qa1.y : qa1.x;
            unsigned sx = ((ba.z >> 10) ^ (ba.z >> d)) & 1u;
            sA.z += sx ? -tt : tt;
        }
        {
            float tt = (d == ((ba.w >> 11) & 15)) ? qa1.w : qa1.z;
            unsigned sx = ((ba.w >> 10) ^ (ba.w >> d)) & 1u;
            sA.w += sx ? -tt : tt;
        }
        {
            float tt = (d == ((bb.x >> 11) & 15)) ? qb0.y : qb0.x;
            unsigned sx = ((bb.x >> 10) ^ (bb.x >> d)) & 1u;
            sB.x += sx ? -tt : tt;
        }
        {
            float tt = (d == ((bb.y >> 11) & 15)) ? qb0.w : qb0.z;
            unsigned sx = ((bb.y >> 10) ^ (bb.y >> d)) & 1u;
            sB.y += sx ? -tt : tt;
        }
        {
            float tt = (d == ((bb.z >> 11) & 15)) ? qb1.y : qb1.x;
            unsigned sx = ((bb.z >> 10) ^ (bb.z >> d)) & 1u;
            sB.z += sx ? -tt : tt;
        }
        {
            float tt = (d == ((bb.w >> 11) & 15)) ? qb1.w : qb1.z;
            unsigned sx = ((bb.w >> 10) ^ (bb.w >> d)) & 1u;
            sB.w += sx ? -tt : tt;
        }
    }

    float* dstA = lv + (size_t)n * BB + b4a;
    float* dstB = lv + (size_t)n * BB + b4b;
    if (liveA) {
        if (fa.x == -1 && fa.y == -1 && fa.z == -1 && fa.w == -1) *(float4*)dstA = sA;
        else {
            if (fa.x == -1) dstA[0] = sA.x;
            if (fa.y == -1) dstA[1] = sA.y;
            if (fa.z == -1) dstA[2] = sA.z;
            if (fa.w == -1) dstA[3] = sA.w;
        }
    }
    if (liveB) {
        if (fb.x == -1 && fb.y == -1 && fb.z == -1 && fb.w == -1) *(float4*)dstB = sB;
        else {
            if (fb.x == -1) dstB[0] = sB.x;
            if (fb.y == -1) dstB[1] = sB.y;
            if (fb.z == -1) dstB[2] = sB.z;
            if (fb.w == -1) dstB[3] = sB.w;
        }
    }
}

// persistent grid-strided parity (reads lv signs) with block-level early exit,
// convergence finalization folded into the last-finishing block (ticket).
// mm[b] is set-only within an iteration -> deterministic final state.
__global__ void k_parity(const int* __restrict__ vc, const float* __restrict__ lv,
                         const u8* __restrict__ syndb, int* __restrict__ niter,
                         int* __restrict__ conv, int* __restrict__ mm,
                         int* __restrict__ cnt, int it) {
    __shared__ int s_stop, s_last;
    int b = threadIdx.x;
    bool frozen = (niter[b] != -1);
    volatile int* vmm = (volatile int*)mm;

    for (int m = blockIdx.x; m < MM; m += PAR_BLOCKS) {
        if (b == 0) s_stop = 1;
        __syncthreads();
        bool flagged = frozen || (vmm[b] != 0);
        if (!flagged) s_stop = 0;
        __syncthreads();
        if (s_stop) break;
        if (!flagged) {
            unsigned par = 0;
            #pragma unroll
            for (int d = 0; d < DEG; d++) {
                int c = vc[m * DEG + d];
                if (c < NN) par ^= (lv[(size_t)c * BB + b] <= 0.0f) ? 1u : 0u;
            }
            if (par != (unsigned)syndb[(size_t)m * BB + b]) atomicOr(&mm[b], 1);
        }
    }
    __syncthreads();
    __threadfence();
    if (b == 0) {
        int tk = atomicAdd(cnt, 1);
        s_last = (tk == PAR_BLOCKS - 1) ? 1 : 0;
    }
    __syncthreads();
    if (s_last) {
        int mmv = atomicAdd(&mm[b], 0);   // device-scope coherent read
        if (niter[b] == -1 && mmv == 0) { niter[b] = it; conv[b] = 1; }
        mm[b] = 0;
        if (b == 0) *cnt = 0;
    }
}

// ---------------- epilogue (fused: one lv read -> both outputs) ----------------

__global__ void k_out_both(const float* __restrict__ lv, float* __restrict__ out_l,
                           float* __restrict__ out_e) {
    __shared__ float tile[64][65];
    int c0 = blockIdx.x * 64;   // b
    int r0 = blockIdx.y * 64;   // n
    #pragma unroll
    for (int k = 0; k < 16; k++) {
        int idx = k * 256 + threadIdx.x;
        int i = idx >> 6, j = idx & 63;
        tile[i][j] = lv[(size_t)(r0 + i) * BB + (c0 + j)];
    }
    __syncthreads();
    #pragma unroll
    for (int k = 0; k < 16; k++) {
        int idx = k * 256 + threadIdx.x;
        int i = idx >> 6, j = idx & 63;
        float v = tile[j][i];
        size_t o = (size_t)(c0 + i) * NN + (r0 + j);
        out_l[o] = v;
        out_e[o] = (v <= 0.0f) ? 1.0f : 0.0f;
    }
}

__global__ void k_out_scalars(const int* __restrict__ niter, const int* __restrict__ conv,
                              float* __restrict__ out_ni, float* __restrict__ out_conv) {
    int b = threadIdx.x;
    int ni = niter[b];
    out_ni[b] = (float)(ni == -1 ? MAX_ITER : ni);
    out_conv[b] = (float)conv[b];
}

// ---------------- launch ----------------

extern "C" void kernel_launch(void* const* d_in, const int* in_sizes, int n_in,
                              void* d_out, int out_size, void* d_ws, size_t ws_size,
                              hipStream_t stream) {
    const float* synd = (const float*)d_in[0];   // (B, M)
    const float* llr0 = (const float*)d_in[1];   // (B, N)
    const int* vcol   = (const int*)d_in[3];     // (M, DEG)
    float* out = (float*)d_out;

    char* ws = (char*)d_ws;
    size_t off = 0;
    auto alloc = [&](size_t bytes) {
        off = (off + 255) & ~(size_t)255;
        size_t o = off; off += bytes; return o;
    };
    float* llr0t  = (float*)(ws + alloc((size_t)NN * BB * 4));
    float* lv     = (float*)(ws + alloc((size_t)NN * BB * 4));
    float* svv    = (float*)(ws + alloc((size_t)MM * BB * 8));   // interleaved {v0,v1}
    u16*   sbits  = (u16*)(ws + alloc((size_t)MM * BB * 2));
    u8*   syndb   = (u8*)(ws + alloc((size_t)MM * BB));
    int* coledges = (int*)(ws + alloc((size_t)MM * DEG * 4));
    int* posinfo  = (int*)(ws + alloc((size_t)MM * DEG * 4));
    int* colptr   = (int*)(ws + alloc((size_t)(NN + 1) * 4));
    int* colcnt   = (int*)(ws + alloc((size_t)NN * 4));
    int* colfill  = (int*)(ws + alloc((size_t)NN * 4));
    int* mm       = (int*)(ws + alloc((size_t)BB * 4));
    int* niter    = (int*)(ws + alloc((size_t)BB * 4));
    int* conv     = (int*)(ws + alloc((size_t)BB * 4));
    int* cnt      = (int*)(ws + alloc(256));
    (void)in_sizes; (void)n_in; (void)out_size; (void)ws_size;

    // prologue
    k_init<<<NN / 256, 256, 0, stream>>>(colcnt, colfill, mm, niter, conv, cnt);
    k_transpose_f32<<<dim3(NN / 64, BB / 64), 256, 0, stream>>>(llr0, llr0t, lv, BB, NN);
    k_synd_t<<<dim3(MM / 64, BB / 64), 256, 0, stream>>>(synd, syndb);
    k_hist<<<(MM * DEG + 255) / 256, 256, 0, stream>>>(vcol, colcnt);
    k_scan<<<1, 256, 0, stream>>>(colcnt, colptr);
    k_fill<<<(MM * DEG + 255) / 256, 256, 0, stream>>>(vcol, colptr, colfill, coledges);
    k_sort<<<NN / 256, 256, 0, stream>>>(colptr, coledges);
    k_pos<<<(MM * DEG + 255) / 256, 256, 0, stream>>>(coledges, colptr, posinfo);

    // main loop (XCD-partitioned, 8-batch threads; standalone early-exit parity)
    for (int i = 1; i <= MAX_ITER; i++) {
        float beta = 1.0f - ldexpf(1.0f, -i);
        k_check8<<<(MM / 64) * NXCD, 256, 0, stream>>>(vcol, lv, svv, sbits, syndb,
                                                       beta, (i == 1) ? 1 : 0);
        k_var8<<<(NN / 64) * NXCD, 256, 0, stream>>>(llr0t, svv, sbits, colptr,
                                                     posinfo, lv, niter);
        k_parity<<<PAR_BLOCKS, 256, 0, stream>>>(vcol, lv, syndb, niter, conv, mm, cnt, i);
    }

    // epilogue: e_out | num_iters | l_out | conv
    float* out_e    = out;
    float* out_ni   = out + (size_t)BB * NN;
    float* out_l    = out + (size_t)BB * NN + BB;
    float* out_conv = out + 2 * (size_t)BB * NN + BB;
    k_out_both<<<dim3(BB / 64, NN / 64), 256, 0, stream>>>(lv, out_l, out_e);
    k_out_scalars<<<1, 256, 0, stream>>>(niter, conv, out_ni, out_conv);
}

// Round 15
// 1712.275 us; speedup vs baseline: 1.0520x; 1.0520x over previous
//
#include <hip/hip_runtime.h>
#include <cmath>
#include <cstdint>
#include <cstddef>

#define BB 256      // batch
#define MM 8192     // checks
#define NN 16384    // variables
#define DEG 10
#define MAX_ITER 30
#define PAR_BLOCKS 64
#define NXCD 8
#define GRP 32      // batches per XCD group (BB / NXCD)

typedef unsigned char  u8;
typedef unsigned short u16;

// ---------------- prologue kernels ----------------

__global__ void k_init(int* colcnt, int* colfill, int* mm, int* niter, int* conv, int* cnt) {
    int t = blockIdx.x * blockDim.x + threadIdx.x;
    if (t < NN) { colcnt[t] = 0; colfill[t] = 0; }
    if (t < BB) { mm[t] = 0; niter[t] = -1; conv[t] = 0; }
    if (t == 0) *cnt = 0;
}

// transpose f32: in (R,C) row-major -> out (C,R); optional duplicate out2
__global__ void k_transpose_f32(const float* __restrict__ in, float* __restrict__ out,
                                float* __restrict__ out2, int R, int C) {
    __shared__ float tile[64][65];
    int c0 = blockIdx.x * 64;
    int r0 = blockIdx.y * 64;
    #pragma unroll
    for (int k = 0; k < 16; k++) {
        int idx = k * 256 + threadIdx.x;
        int i = idx >> 6, j = idx & 63;
        tile[i][j] = in[(size_t)(r0 + i) * C + (c0 + j)];
    }
    __syncthreads();
    #pragma unroll
    for (int k = 0; k < 16; k++) {
        int idx = k * 256 + threadIdx.x;
        int i = idx >> 6, j = idx & 63;
        float v = tile[j][i];
        size_t o = (size_t)(c0 + i) * R + (r0 + j);
        out[o] = v;
        if (out2) out2[o] = v;
    }
}

// synd (B,M) f32 -> syndb (M,B) byte
__global__ void k_synd_t(const float* __restrict__ synd, u8* __restrict__ syndb) {
    __shared__ float tile[64][65];
    int c0 = blockIdx.x * 64;   // m
    int r0 = blockIdx.y * 64;   // b
    #pragma unroll
    for (int k = 0; k < 16; k++) {
        int idx = k * 256 + threadIdx.x;
        int i = idx >> 6, j = idx & 63;
        tile[i][j] = synd[(size_t)(r0 + i) * MM + (c0 + j)];
    }
    __syncthreads();
    #pragma unroll
    for (int k = 0; k < 16; k++) {
        int idx = k * 256 + threadIdx.x;
        int i = idx >> 6, j = idx & 63;
        syndb[(size_t)(c0 + i) * BB + (r0 + j)] = (tile[j][i] != 0.0f) ? 1 : 0;
    }
}

__global__ void k_hist(const int* __restrict__ vc, int* colcnt) {
    int e = blockIdx.x * 256 + threadIdx.x;
    if (e >= MM * DEG) return;
    int c = vc[e];
    if (c < NN) atomicAdd(&colcnt[c], 1);
}

__global__ void k_scan(const int* __restrict__ colcnt, int* __restrict__ colptr) {
    __shared__ int part[256];
    __shared__ int base[257];
    int t = threadIdx.x;
    int s = 0;
    for (int i = 0; i < 64; i++) s += colcnt[t * 64 + i];
    part[t] = s;
    __syncthreads();
    if (t == 0) {
        int acc = 0;
        for (int i = 0; i < 256; i++) { base[i] = acc; acc += part[i]; }
        base[256] = acc;
    }
    __syncthreads();
    int acc = base[t];
    for (int i = 0; i < 64; i++) { int c = t * 64 + i; colptr[c] = acc; acc += colcnt[c]; }
    if (t == 255) colptr[NN] = base[256];
}

__global__ void k_fill(const int* __restrict__ vc, const int* __restrict__ colptr,
                       int* colfill, int* coledges) {
    int e = blockIdx.x * 256 + threadIdx.x;
    if (e >= MM * DEG) return;
    int c = vc[e];
    if (c < NN) {
        int p = colptr[c] + atomicAdd(&colfill[c], 1);
        coledges[p] = e;
    }
}

// deterministic: sort each column's edge list ascending (order-independent result)
__global__ void k_sort(const int* __restrict__ colptr, int* coledges) {
    int n = blockIdx.x * 256 + threadIdx.x;
    if (n >= NN) return;
    int p0 = colptr[n], p1 = colptr[n + 1];
    for (int i = p0 + 1; i < p1; i++) {
        int v = coledges[i];
        int j = i - 1;
        while (j >= p0 && coledges[j] > v) { coledges[j + 1] = coledges[j]; j--; }
        coledges[j + 1] = v;
    }
}

// ---------------- iteration kernels (R9/R13 proven structure) ----------------

// check-node update, XCD-partitioned over batch groups.
// bid&7 = batch group (round-robin block->XCD), bid>>3 = row chunk of 32.
// thread t: row = chunk*32 + (t>>3), batches b4 = group*32 + (t&7)*4.
// State per (m,b): svv interleaved {v0,v1} (v0=beta*min0, v1=beta*min1),
// sbits = neg(10b) | q<<10 | i0<<11. Prev-message reconstruction is bit-exact:
// +-1 multiplies exact; (d==i0) <=> (ab[d]==min0) since dup mins force min1==min0.
__global__ void k_check4(const int* __restrict__ vc, const float* __restrict__ lv,
                         float* __restrict__ svv, u16* __restrict__ sbits,
                         const u8* __restrict__ syndb, float beta, int first) {
    __shared__ int cs[32 * DEG];
    int bid = blockIdx.x, t = threadIdx.x;
    int g = bid & (NXCD - 1);
    int r0 = (bid >> 3) * 32;
    for (int i = t; i < 32 * DEG; i += 256) cs[i] = vc[r0 * DEG + i];
    __syncthreads();

    int row = t >> 3;
    int m = r0 + row;
    int b4 = g * GRP + (t & 7) * 4;
    size_t mb = (size_t)m * BB + b4;

    float pv0[4], pv1[4];
    unsigned pb[4];
    if (!first) {
        float4 q0 = *(const float4*)(svv + mb * 2);
        float4 q1 = *(const float4*)(svv + mb * 2 + 4);
        ushort4 pbv = *(const ushort4*)(sbits + mb);
        pv0[0] = q0.x; pv1[0] = q0.y; pv0[1] = q0.z; pv1[1] = q0.w;
        pv0[2] = q1.x; pv1[2] = q1.y; pv0[3] = q1.z; pv1[3] = q1.w;
        pb[0] = pbv.x; pb[1] = pbv.y; pb[2] = pbv.z; pb[3] = pbv.w;
    } else {
        #pragma unroll
        for (int j = 0; j < 4; j++) { pv0[j] = 0.f; pv1[j] = 0.f; pb[j] = 0; }
    }
    int pi0[4]; unsigned pq[4];
    #pragma unroll
    for (int j = 0; j < 4; j++) { pi0[j] = (pb[j] >> 11) & 15; pq[j] = (pb[j] >> 10) & 1u; }

    float m0[4] = {INFINITY, INFINITY, INFINITY, INFINITY};
    float m1[4] = {INFINITY, INFINITY, INFINITY, INFINITY};
    unsigned neg[4] = {0, 0, 0, 0};
    int i0[4] = {0, 0, 0, 0};

    #pragma unroll
    for (int d = 0; d < DEG; d++) {
        int c = cs[row * DEG + d];
        if (c >= NN) continue;   // dummy edge: a=+inf -> no sign bit, no min update
        float4 gv = *(const float4*)(lv + (size_t)c * BB + b4);
        float gj[4] = {gv.x, gv.y, gv.z, gv.w};
        #pragma unroll
        for (int j = 0; j < 4; j++) {
            float a;
            if (first) a = gj[j];
            else {
                float tt = (d == pi0[j]) ? pv1[j] : pv0[j];
                unsigned sx = pq[j] ^ ((pb[j] >> d) & 1u);
                a = gj[j] - (sx ? -tt : tt);
            }
            if (!(a > 0.0f)) neg[j] |= 1u << d;   // sign(0) -> -1 semantics
            float x = fabsf(a);
            if (x < m0[j]) { m1[j] = m0[j]; m0[j] = x; i0[j] = d; }
            else if (x < m1[j]) m1[j] = x;
        }
    }

    uchar4 sb = *(const uchar4*)(syndb + mb);
    unsigned sbv[4] = {sb.x, sb.y, sb.z, sb.w};
    unsigned q[4];
    #pragma unroll
    for (int j = 0; j < 4; j++)
        q[j] = (__popc(neg[j]) & 1u) ^ (sbv[j] ? 1u : 0u);

    float v0[4], v1[4];
    #pragma unroll
    for (int j = 0; j < 4; j++) { v0[j] = beta * m0[j]; v1[j] = beta * m1[j]; }

    *(float4*)(svv + mb * 2)     = make_float4(v0[0], v1[0], v0[1], v1[1]);
    *(float4*)(svv + mb * 2 + 4) = make_float4(v0[2], v1[2], v0[3], v1[3]);
    ushort4 nb;
    nb.x = (u16)(neg[0] | (q[0] << 10) | ((unsigned)i0[0] << 11));
    nb.y = (u16)(neg[1] | (q[1] << 10) | ((unsigned)i0[1] << 11));
    nb.z = (u16)(neg[2] | (q[2] << 10) | ((unsigned)i0[2] << 11));
    nb.w = (u16)(neg[3] | (q[3] << 10) | ((unsigned)i0[3] << 11));
    *(ushort4*)(sbits + mb) = nb;
}

// variable-node update, XCD-partitioned over batch groups (same mapping).
// Deterministic ascending-edge sum; messages reconstructed bit-exactly.
__global__ void k_var4(const float* __restrict__ llr0t, const float* __restrict__ svv,
                       const u16* __restrict__ sbits,
                       const int* __restrict__ colptr, const int* __restrict__ coledges,
                       float* __restrict__ lv, const int* __restrict__ niter) {
    int bid = blockIdx.x, t = threadIdx.x;
    int g = bid & (NXCD - 1);
    int n0 = (bid >> 3) * 32;
    int n = n0 + (t >> 3);
    int b4 = g * GRP + (t & 7) * 4;

    int4 f = *(const int4*)(niter + b4);
    if (f.x != -1 && f.y != -1 && f.z != -1 && f.w != -1) return;

    float4 s = *(const float4*)(llr0t + (size_t)n * BB + b4);
    int p0 = colptr[n], p1 = colptr[n + 1];
    for (int pp = p0; pp < p1; pp++) {
        int e = coledges[pp];
        int m = e / DEG;
        int d = e - m * DEG;
        size_t mb = (size_t)m * BB + b4;
        float4 q0 = *(const float4*)(svv + mb * 2);
        float4 q1 = *(const float4*)(svv + mb * 2 + 4);
        ushort4 bb = *(const ushort4*)(sbits + mb);
        {
            float tt = (d == ((bb.x >> 11) & 15)) ? q0.y : q0.x;
            unsigned sx = ((bb.x >> 10) ^ (bb.x >> d)) & 1u;
            s.x += sx ? -tt : tt;
        }
        {
            float tt = (d == ((bb.y >> 11) & 15)) ? q0.w : q0.z;
            unsigned sx = ((bb.y >> 10) ^ (bb.y >> d)) & 1u;
            s.y += sx ? -tt : tt;
        }
        {
            float tt = (d == ((bb.z >> 11) & 15)) ? q1.y : q1.x;
            unsigned sx = ((bb.z >> 10) ^ (bb.z >> d)) & 1u;
            s.z += sx ? -tt : tt;
        }
        {
            float tt = (d == ((bb.w >> 11) & 15)) ? q1.w : q1.z;
            unsigned sx = ((bb.w >> 10) ^ (bb.w >> d)) & 1u;
            s.w += sx ? -tt : tt;
        }
    }
    float* dst = lv + (size_t)n * BB + b4;
    if (f.x == -1 && f.y == -1 && f.z == -1 && f.w == -1) {
        *(float4*)dst = s;
    } else {
        if (f.x == -1) dst[0] = s.x;
        if (f.y == -1) dst[1] = s.y;
        if (f.z == -1) dst[2] = s.z;
        if (f.w == -1) dst[3] = s.w;
    }
}

// persistent grid-strided parity (reads lv signs) with block-level early exit,
// convergence finalization folded into the last-finishing block (ticket).
// mm[b] is set-only within an iteration -> deterministic final state.
__global__ void k_parity(const int* __restrict__ vc, const float* __restrict__ lv,
                         const u8* __restrict__ syndb, int* __restrict__ niter,
                         int* __restrict__ conv, int* __restrict__ mm,
                         int* __restrict__ cnt, int it) {
    __shared__ int s_stop, s_last;
    int b = threadIdx.x;
    bool frozen = (niter[b] != -1);
    volatile int* vmm = (volatile int*)mm;

    for (int m = blockIdx.x; m < MM; m += PAR_BLOCKS) {
        if (b == 0) s_stop = 1;
        __syncthreads();
        bool flagged = frozen || (vmm[b] != 0);
        if (!flagged) s_stop = 0;
        __syncthreads();
        if (s_stop) break;
        if (!flagged) {
            unsigned par = 0;
            #pragma unroll
            for (int d = 0; d < DEG; d++) {
                int c = vc[m * DEG + d];
                if (c < NN) par ^= (lv[(size_t)c * BB + b] <= 0.0f) ? 1u : 0u;
            }
            if (par != (unsigned)syndb[(size_t)m * BB + b]) atomicOr(&mm[b], 1);
        }
    }
    __syncthreads();
    __threadfence();
    if (b == 0) {
        int tk = atomicAdd(cnt, 1);
        s_last = (tk == PAR_BLOCKS - 1) ? 1 : 0;
    }
    __syncthreads();
    if (s_last) {
        int mmv = atomicAdd(&mm[b], 0);   // device-scope coherent read
        if (niter[b] == -1 && mmv == 0) { niter[b] = it; conv[b] = 1; }
        mm[b] = 0;
        if (b == 0) *cnt = 0;
    }
}

// ---------------- epilogue (fused: one lv read -> both outputs) ----------------

__global__ void k_out_both(const float* __restrict__ lv, float* __restrict__ out_l,
                           float* __restrict__ out_e) {
    __shared__ float tile[64][65];
    int c0 = blockIdx.x * 64;   // b
    int r0 = blockIdx.y * 64;   // n
    #pragma unroll
    for (int k = 0; k < 16; k++) {
        int idx = k * 256 + threadIdx.x;
        int i = idx >> 6, j = idx & 63;
        tile[i][j] = lv[(size_t)(r0 + i) * BB + (c0 + j)];
    }
    __syncthreads();
    #pragma unroll
    for (int k = 0; k < 16; k++) {
        int idx = k * 256 + threadIdx.x;
        int i = idx >> 6, j = idx & 63;
        float v = tile[j][i];
        size_t o = (size_t)(c0 + i) * NN + (r0 + j);
        out_l[o] = v;
        out_e[o] = (v <= 0.0f) ? 1.0f : 0.0f;
    }
}

__global__ void k_out_scalars(const int* __restrict__ niter, const int* __restrict__ conv,
                              float* __restrict__ out_ni, float* __restrict__ out_conv) {
    int b = threadIdx.x;
    int ni = niter[b];
    out_ni[b] = (float)(ni == -1 ? MAX_ITER : ni);
    out_conv[b] = (float)conv[b];
}

// ---------------- launch ----------------

extern "C" void kernel_launch(void* const* d_in, const int* in_sizes, int n_in,
                              void* d_out, int out_size, void* d_ws, size_t ws_size,
                              hipStream_t stream) {
    const float* synd = (const float*)d_in[0];   // (B, M)
    const float* llr0 = (const float*)d_in[1];   // (B, N)
    const int* vcol   = (const int*)d_in[3];     // (M, DEG)
    float* out = (float*)d_out;

    char* ws = (char*)d_ws;
    size_t off = 0;
    auto alloc = [&](size_t bytes) {
        off = (off + 255) & ~(size_t)255;
        size_t o = off; off += bytes; return o;
    };
    float* llr0t  = (float*)(ws + alloc((size_t)NN * BB * 4));
    float* lv     = (float*)(ws + alloc((size_t)NN * BB * 4));
    float* svv    = (float*)(ws + alloc((size_t)MM * BB * 8));   // interleaved {v0,v1}
    u16*   sbits  = (u16*)(ws + alloc((size_t)MM * BB * 2));
    u8*   syndb   = (u8*)(ws + alloc((size_t)MM * BB));
    int* coledges = (int*)(ws + alloc((size_t)MM * DEG * 4));
    int* colptr   = (int*)(ws + alloc((size_t)(NN + 1) * 4));
    int* colcnt   = (int*)(ws + alloc((size_t)NN * 4));
    int* colfill  = (int*)(ws + alloc((size_t)NN * 4));
    int* mm       = (int*)(ws + alloc((size_t)BB * 4));
    int* niter    = (int*)(ws + alloc((size_t)BB * 4));
    int* conv     = (int*)(ws + alloc((size_t)BB * 4));
    int* cnt      = (int*)(ws + alloc(256));
    (void)in_sizes; (void)n_in; (void)out_size; (void)ws_size;

    // prologue
    k_init<<<NN / 256, 256, 0, stream>>>(colcnt, colfill, mm, niter, conv, cnt);
    k_transpose_f32<<<dim3(NN / 64, BB / 64), 256, 0, stream>>>(llr0, llr0t, lv, BB, NN);
    k_synd_t<<<dim3(MM / 64, BB / 64), 256, 0, stream>>>(synd, syndb);
    k_hist<<<(MM * DEG + 255) / 256, 256, 0, stream>>>(vcol, colcnt);
    k_scan<<<1, 256, 0, stream>>>(colcnt, colptr);
    k_fill<<<(MM * DEG + 255) / 256, 256, 0, stream>>>(vcol, colptr, colfill, coledges);
    k_sort<<<NN / 256, 256, 0, stream>>>(colptr, coledges);

    // main loop (R13 proven structure: XCD-partitioned check/var + early-exit parity)
    for (int i = 1; i <= MAX_ITER; i++) {
        float beta = 1.0f - ldexpf(1.0f, -i);
        k_check4<<<(MM / 32) * NXCD, 256, 0, stream>>>(vcol, lv, svv, sbits, syndb,
                                                       beta, (i == 1) ? 1 : 0);
        k_var4<<<(NN / 32) * NXCD, 256, 0, stream>>>(llr0t, svv, sbits, colptr,
                                                     coledges, lv, niter);
        k_parity<<<PAR_BLOCKS, 256, 0, stream>>>(vcol, lv, syndb, niter, conv, mm, cnt, i);
    }

    // epilogue: e_out | num_iters | l_out | conv
    float* out_e    = out;
    float* out_ni   = out + (size_t)BB * NN;
    float* out_l    = out + (size_t)BB * NN + BB;
    float* out_conv = out + 2 * (size_t)BB * NN + BB;
    k_out_both<<<dim3(BB / 64, NN / 64), 256, 0, stream>>>(lv, out_l, out_e);
    k_out_scalars<<<1, 256, 0, stream>>>(niter, conv, out_ni, out_conv);
}